// Round 1
// baseline (484.390 us; speedup 1.0000x reference)
//
#include <hip/hip_runtime.h>
#include <math.h>

#define BB 2
#define II 256
#define DD 768
#define HH 12
#define DPP 128
#define DKK 64
#define NPQ 4
#define NPV 8
#define FEAT_DIM 2304
#define MM (BB*II)

// ---------------- workspace layout (floats) ----------------
#define OFF_Q    ((size_t)0)
#define OFF_K    ((size_t)393216)
#define OFF_V    ((size_t)786432)
#define OFF_QGP  ((size_t)1179648)   // 73728
#define OFF_KGP  ((size_t)1253376)   // 73728
#define OFF_VGP  ((size_t)1327104)   // 147456
#define OFF_QGL  ((size_t)1474560)   // 73728
#define OFF_KGL  ((size_t)1548288)   // 73728
#define OFF_VGL  ((size_t)1622016)   // 147456
#define OFF_PB   ((size_t)1769472)   // [b][i][j][h] 1572864
#define OFF_ATTN ((size_t)3342336)   // [b][h][i][j] 1572864
#define OFF_FEAT ((size_t)4915200)   // [b][i][2304] 1179648

#define SCALAR_W 0.07216878364870323f   /* 1/sqrt(192) */
#define POINT_W  0.13608276348795434f   /* 1/sqrt(54)  */
#define PAIR_W   0.57735026918962576f   /* 1/sqrt(3)   */

struct GemmJob { const float* W; float* out; int N; };
struct GemmJobs { GemmJob j[6]; };

// out[m][n] = sum_k A[m][k] * W[k][n] (+ bias[n])
// tile: 16 rows x 64 cols per block, 256 threads, 4 outputs/thread
__global__ __launch_bounds__(256)
void gemm_batch_kernel(const float* __restrict__ A, GemmJobs jobs,
                       const float* __restrict__ bias, int K) {
  const GemmJob J = jobs.j[blockIdx.z];
  const int N = J.N;
  const int n0 = blockIdx.y * 64;
  if (n0 >= N) return;
  const int m0 = blockIdx.x * 16;
  __shared__ float a_s[16][32];
  __shared__ float w_s[32][64];
  const int tid = threadIdx.x;
  const int row = tid >> 4;          // 0..15
  const int col = (tid & 15) << 2;   // 0..60
  float acc0 = 0.f, acc1 = 0.f, acc2 = 0.f, acc3 = 0.f;
  for (int kc = 0; kc < K; kc += 32) {
#pragma unroll
    for (int u = 0; u < 2; ++u) {
      int idx = tid + u * 256;
      a_s[idx >> 5][idx & 31] = A[(size_t)(m0 + (idx >> 5)) * K + kc + (idx & 31)];
    }
#pragma unroll
    for (int u = 0; u < 8; ++u) {
      int idx = tid + u * 256;
      int kk = idx >> 6, c = idx & 63;
      int nc = n0 + c;
      w_s[kk][c] = (nc < N) ? J.W[(size_t)(kc + kk) * N + nc] : 0.f;
    }
    __syncthreads();
#pragma unroll
    for (int kk = 0; kk < 32; ++kk) {
      const float a = a_s[row][kk];
      const float4 w = *reinterpret_cast<const float4*>(&w_s[kk][col]);
      acc0 += a * w.x; acc1 += a * w.y; acc2 += a * w.z; acc3 += a * w.w;
    }
    __syncthreads();
  }
  const int orow = m0 + row;
  const int oc = n0 + col;
  float* o = J.out + (size_t)orow * N;
  if (oc + 0 < N) o[oc + 0] = acc0 + (bias ? bias[oc + 0] : 0.f);
  if (oc + 1 < N) o[oc + 1] = acc1 + (bias ? bias[oc + 1] : 0.f);
  if (oc + 2 < N) o[oc + 2] = acc2 + (bias ? bias[oc + 2] : 0.f);
  if (oc + 3 < N) o[oc + 3] = acc3 + (bias ? bias[oc + 3] : 0.f);
}

struct XfJob { float* buf; const float* T; const float* R; int np; };
struct XfJobs { XfJob j[6]; };

// in-place: pt -> R^T * pt + T   (reference: einsum('bipq,bihcq', IR, pts)+T with IR=R^T)
__global__ __launch_bounds__(256)
void transform_kernel(XfJobs jobs) {
  const XfJob J = jobs.j[blockIdx.y];
  const int total = BB * II * HH * J.np;
  const int idx = blockIdx.x * 256 + threadIdx.x;
  if (idx >= total) return;
  const int bi = idx / (HH * J.np);
  const size_t base = (size_t)idx * 3;
  const float p0 = J.buf[base + 0], p1 = J.buf[base + 1], p2 = J.buf[base + 2];
  const float* R = J.R + (size_t)bi * 9;
  const float* T = J.T + (size_t)bi * 3;
  J.buf[base + 0] = R[0] * p0 + R[3] * p1 + R[6] * p2 + T[0];
  J.buf[base + 1] = R[1] * p0 + R[4] * p1 + R[7] * p2 + T[1];
  J.buf[base + 2] = R[2] * p0 + R[5] * p1 + R[8] * p2 + T[2];
}

// pb[b][i][j][h] = pair_w * sum_p x2d[b,i,j,p] * Wpb[p,h]
__global__ __launch_bounds__(256)
void pairbias_kernel(const float* __restrict__ x2d, const float* __restrict__ Wpb,
                     float* __restrict__ pb) {
  __shared__ float w_s[DPP][HH];
  const int tid = threadIdx.x;
  for (int idx = tid; idx < DPP * HH; idx += 256) w_s[idx / HH][idx % HH] = Wpb[idx];
  __syncthreads();
  const size_t bi = blockIdx.x;                     // b*II + i
  const float* xr = x2d + (bi * II + tid) * DPP;    // this thread's j-row
  float acc[HH];
#pragma unroll
  for (int h = 0; h < HH; ++h) acc[h] = 0.f;
  for (int p = 0; p < DPP; p += 4) {
    const float4 x4 = *reinterpret_cast<const float4*>(&xr[p]);
    const float xs[4] = {x4.x, x4.y, x4.z, x4.w};
#pragma unroll
    for (int u = 0; u < 4; ++u) {
      const float x = xs[u];
      const float4 w0 = *reinterpret_cast<const float4*>(&w_s[p + u][0]);
      const float4 w1 = *reinterpret_cast<const float4*>(&w_s[p + u][4]);
      const float4 w2 = *reinterpret_cast<const float4*>(&w_s[p + u][8]);
      acc[0] += x * w0.x; acc[1] += x * w0.y; acc[2]  += x * w0.z; acc[3]  += x * w0.w;
      acc[4] += x * w1.x; acc[5] += x * w1.y; acc[6]  += x * w1.z; acc[7]  += x * w1.w;
      acc[8] += x * w2.x; acc[9] += x * w2.y; acc[10] += x * w2.z; acc[11] += x * w2.w;
    }
  }
  float* o = pb + (bi * II + tid) * HH;
#pragma unroll
  for (int h = 0; h < HH; ++h) o[h] = PAIR_W * acc[h];
}

// one block per (b,h,i); thread j computes logit, block softmax over j
__global__ __launch_bounds__(256)
void logits_softmax_kernel(const float* __restrict__ q, const float* __restrict__ k,
                           const float* __restrict__ qgp, const float* __restrict__ kgp,
                           const float* __restrict__ qgl, const float* __restrict__ kgl,
                           const float* __restrict__ pb, const float* __restrict__ bias,
                           const float* __restrict__ tpw_past, const float* __restrict__ tpw_last,
                           float* __restrict__ attn) {
  const int blk = blockIdx.x;
  const int i = blk % II;
  const int h = (blk / II) % HH;
  const int b = blk / (II * HH);
  __shared__ float q_s[DKK];
  __shared__ float qgp_s[12];
  __shared__ float qgl_s[12];
  __shared__ float red[256];
  const int tid = threadIdx.x;
  if (tid < DKK) q_s[tid] = q[((size_t)(b * II + i)) * DD + h * DKK + tid];
  if (tid >= 64 && tid < 76)  qgp_s[tid - 64] = qgp[((size_t)(b * II + i) * HH + h) * 12 + (tid - 64)];
  if (tid >= 96 && tid < 108) qgl_s[tid - 96] = qgl[((size_t)(b * II + i) * HH + h) * 12 + (tid - 96)];
  __syncthreads();
  const float pwp = POINT_W * log1pf(expf(tpw_past[h]));
  const float pwl = POINT_W * log1pf(expf(tpw_last[h]));
  const int j = tid;
  // scalar q.k
  const float4* kr = reinterpret_cast<const float4*>(k + ((size_t)(b * II + j)) * DD + h * DKK);
  const float4* qs4 = reinterpret_cast<const float4*>(q_s);
  float s = 0.f;
#pragma unroll
  for (int c = 0; c < 16; ++c) {
    const float4 kv = kr[c];
    const float4 qv = qs4[c];
    s += qv.x * kv.x + qv.y * kv.y + qv.z * kv.z + qv.w * kv.w;
  }
  float logit = SCALAR_W * s;
  // point distances (past)
  {
    const float* kp = kgp + ((size_t)(b * II + j) * HH + h) * 12;
    float d = 0.f;
#pragma unroll
    for (int n = 0; n < NPQ; ++n) {
      const float dx = qgp_s[n * 3 + 0] - kp[n * 3 + 0];
      const float dy = qgp_s[n * 3 + 1] - kp[n * 3 + 1];
      const float dz = qgp_s[n * 3 + 2] - kp[n * 3 + 2];
      d += sqrtf(dx * dx + dy * dy + dz * dz);
    }
    logit -= 0.5f * pwp * d;
  }
  // point distances (last)
  {
    const float* kp = kgl + ((size_t)(b * II + j) * HH + h) * 12;
    float d = 0.f;
#pragma unroll
    for (int n = 0; n < NPQ; ++n) {
      const float dx = qgl_s[n * 3 + 0] - kp[n * 3 + 0];
      const float dy = qgl_s[n * 3 + 1] - kp[n * 3 + 1];
      const float dz = qgl_s[n * 3 + 2] - kp[n * 3 + 2];
      d += sqrtf(dx * dx + dy * dy + dz * dz);
    }
    logit -= 0.5f * pwl * d;
  }
  logit += pb[((size_t)(b * II + i) * II + j) * HH + h];
  logit += bias[((size_t)(b * HH + h) * II + i) * II + j];
  // softmax over j
  red[tid] = logit; __syncthreads();
  for (int off = 128; off > 0; off >>= 1) {
    if (tid < off) red[tid] = fmaxf(red[tid], red[tid + off]);
    __syncthreads();
  }
  const float m = red[0]; __syncthreads();
  const float e = expf(logit - m);
  red[tid] = e; __syncthreads();
  for (int off = 128; off > 0; off >>= 1) {
    if (tid < off) red[tid] += red[tid + off];
    __syncthreads();
  }
  attn[((size_t)(b * HH + h) * II + i) * II + j] = e / red[0];
}

// block per (b,i), 128 threads: t[h][p] = sum_j attn*x2d; feat[0:768) = t @ W_pair_value
__global__ __launch_bounds__(128)
void wpair_kernel(const float* __restrict__ x2d, const float* __restrict__ attn,
                  const float* __restrict__ Wpv, float* __restrict__ feat) {
  __shared__ float a_s[HH][II];
  __shared__ float t_s[HH][DPP];
  const int tid = threadIdx.x;
  const int bi = blockIdx.x;
  const int b = bi >> 8;
  const int i = bi & 255;
  for (int idx = tid; idx < HH * II; idx += 128) {
    const int h = idx >> 8, j = idx & 255;
    a_s[h][j] = attn[((size_t)(b * HH + h) * II + i) * II + j];
  }
  __syncthreads();
  float acc[HH];
#pragma unroll
  for (int h = 0; h < HH; ++h) acc[h] = 0.f;
  const float* xr = x2d + ((size_t)bi * II) * DPP + tid;
  for (int j = 0; j < II; j += 4) {
    const float x0 = xr[(size_t)(j + 0) * DPP];
    const float x1 = xr[(size_t)(j + 1) * DPP];
    const float x2 = xr[(size_t)(j + 2) * DPP];
    const float x3 = xr[(size_t)(j + 3) * DPP];
#pragma unroll
    for (int h = 0; h < HH; ++h) {
      const float4 a = *reinterpret_cast<const float4*>(&a_s[h][j]);
      acc[h] += a.x * x0 + a.y * x1 + a.z * x2 + a.w * x3;
    }
  }
#pragma unroll
  for (int h = 0; h < HH; ++h) t_s[h][tid] = acc[h];
  __syncthreads();
  float* fout = feat + (size_t)bi * FEAT_DIM;
  for (int c = tid; c < DD; c += 128) {
    const int h = c >> 6;
    float o = 0.f;
    for (int p = 0; p < DPP; ++p) o += t_s[h][p] * Wpv[(size_t)p * DD + c];
    fout[c] = o;
  }
}

// block per (b,i), 256 threads: out_scalar, og(past/last), inverse transform + norms
__global__ __launch_bounds__(256)
void av_kernel(const float* __restrict__ attn, const float* __restrict__ v,
               const float* __restrict__ vgp, const float* __restrict__ vgl,
               const float* __restrict__ past_T, const float* __restrict__ past_R,
               float* __restrict__ feat) {
  __shared__ float a_s[HH][II];
  __shared__ float og_s[2][288];
  const int tid = threadIdx.x;
  const int bi = blockIdx.x;
  const int b = bi >> 8;
  const int i = bi & 255;
  for (int idx = tid; idx < HH * II; idx += 256) {
    const int h = idx >> 8, j = idx & 255;
    a_s[h][j] = attn[((size_t)(b * HH + h) * II + i) * II + j];
  }
  __syncthreads();
  float* fout = feat + (size_t)bi * FEAT_DIM;
  // out_scalar
  for (int c = tid; c < DD; c += 256) {
    const int h = c >> 6;
    const float* vb = v + (size_t)b * II * DD + c;
    float o = 0.f;
    for (int j = 0; j < II; j += 4) {
      const float4 a = *reinterpret_cast<const float4*>(&a_s[h][j]);
      o += a.x * vb[(size_t)(j + 0) * DD] + a.y * vb[(size_t)(j + 1) * DD]
         + a.z * vb[(size_t)(j + 2) * DD] + a.w * vb[(size_t)(j + 3) * DD];
    }
    fout[768 + c] = o;
  }
  // og for both branches: 2*288 outputs
  for (int t = tid; t < 576; t += 256) {
    const int br = t / 288;
    const int r = t % 288;           // h*24 + n*3 + p
    const int h = r / 24;
    const int rem = r % 24;
    const float* vg = br ? vgl : vgp;
    const float* vb = vg + (size_t)b * II * 288 + h * 24 + rem;
    float o = 0.f;
    for (int j = 0; j < II; ++j) o += a_s[h][j] * vb[(size_t)j * 288];
    og_s[br][r] = o;
  }
  __syncthreads();
  // inverse with PAST pose (faithful to reference) + norms
  if (tid < 192) {
    const int br = tid / 96;
    const int r = tid % 96;          // h*8 + n
    const int h = r >> 3;
    const int n = r & 7;
    const float* T = past_T + (size_t)bi * 3;
    const float* R = past_R + (size_t)bi * 9;
    const float o0 = og_s[br][h * 24 + n * 3 + 0] - T[0];
    const float o1 = og_s[br][h * 24 + n * 3 + 1] - T[1];
    const float o2 = og_s[br][h * 24 + n * 3 + 2] - T[2];
    const float l0 = R[0] * o0 + R[1] * o1 + R[2] * o2;
    const float l1 = R[3] * o0 + R[4] * o1 + R[5] * o2;
    const float l2 = R[6] * o0 + R[7] * o1 + R[8] * o2;
    const float nn = sqrtf(l0 * l0 + l1 * l1 + l2 * l2);
    const int olbase = br ? 1920 : 1536;
    const int nbase  = br ? 2208 : 1824;
    fout[olbase + r * 3 + 0] = l0;
    fout[olbase + r * 3 + 1] = l1;
    fout[olbase + r * 3 + 2] = l2;
    fout[nbase + r] = nn;
  }
}

extern "C" void kernel_launch(void* const* d_in, const int* in_sizes, int n_in,
                              void* d_out, int out_size, void* d_ws, size_t ws_size,
                              hipStream_t stream) {
  (void)in_sizes; (void)n_in; (void)out_size; (void)ws_size;
  const float* x1d      = (const float*)d_in[0];
  const float* x2d      = (const float*)d_in[1];
  const float* past_T   = (const float*)d_in[2];
  const float* past_R   = (const float*)d_in[3];
  const float* last_T   = (const float*)d_in[4];
  const float* last_R   = (const float*)d_in[5];
  const float* bias     = (const float*)d_in[6];
  const float* Wq       = (const float*)d_in[7];
  const float* Wk       = (const float*)d_in[8];
  const float* Wv       = (const float*)d_in[9];
  const float* Wpb      = (const float*)d_in[10];
  const float* Wpq_past = (const float*)d_in[11];
  const float* Wpk_past = (const float*)d_in[12];
  const float* Wpv_past = (const float*)d_in[13];
  const float* Wpq_last = (const float*)d_in[14];
  const float* Wpk_last = (const float*)d_in[15];
  const float* Wpv_last = (const float*)d_in[16];
  const float* tpw_past = (const float*)d_in[17];
  const float* tpw_last = (const float*)d_in[18];
  const float* W_pair_value = (const float*)d_in[19];
  const float* W_out    = (const float*)d_in[20];
  const float* b_out    = (const float*)d_in[21];
  float* out = (float*)d_out;
  float* ws  = (float*)d_ws;

  float* q    = ws + OFF_Q;
  float* k    = ws + OFF_K;
  float* v    = ws + OFF_V;
  float* qgp  = ws + OFF_QGP;
  float* kgp  = ws + OFF_KGP;
  float* vgp  = ws + OFF_VGP;
  float* qgl  = ws + OFF_QGL;
  float* kgl  = ws + OFF_KGL;
  float* vgl  = ws + OFF_VGL;
  float* pb   = ws + OFF_PB;
  float* attn = ws + OFF_ATTN;
  float* feat = ws + OFF_FEAT;

  const dim3 blk256(256), blk128(128);

  // 1) q,k,v = x1d @ {Wq,Wk,Wv}
  {
    GemmJobs jobs = {};
    jobs.j[0] = {Wq, q, DD};
    jobs.j[1] = {Wk, k, DD};
    jobs.j[2] = {Wv, v, DD};
    jobs.j[3] = {Wq, q, DD}; jobs.j[4] = {Wq, q, DD}; jobs.j[5] = {Wq, q, DD};
    gemm_batch_kernel<<<dim3(32, 12, 3), blk256, 0, stream>>>(x1d, jobs, nullptr, DD);
  }
  // 2) six point projections
  {
    GemmJobs jobs = {};
    jobs.j[0] = {Wpq_past, qgp, HH * NPQ * 3};
    jobs.j[1] = {Wpk_past, kgp, HH * NPQ * 3};
    jobs.j[2] = {Wpv_past, vgp, HH * NPV * 3};
    jobs.j[3] = {Wpq_last, qgl, HH * NPQ * 3};
    jobs.j[4] = {Wpk_last, kgl, HH * NPQ * 3};
    jobs.j[5] = {Wpv_last, vgl, HH * NPV * 3};
    gemm_batch_kernel<<<dim3(32, 5, 6), blk256, 0, stream>>>(x1d, jobs, nullptr, DD);
  }
  // 3) local->global frame transform (in-place)
  {
    XfJobs jobs = {};
    jobs.j[0] = {qgp, past_T, past_R, NPQ};
    jobs.j[1] = {kgp, past_T, past_R, NPQ};
    jobs.j[2] = {vgp, past_T, past_R, NPV};
    jobs.j[3] = {qgl, last_T, last_R, NPQ};
    jobs.j[4] = {kgl, last_T, last_R, NPQ};
    jobs.j[5] = {vgl, last_T, last_R, NPV};
    transform_kernel<<<dim3(192, 6), blk256, 0, stream>>>(jobs);
  }
  // 4) pair bias from x2d
  pairbias_kernel<<<dim3(BB * II), blk256, 0, stream>>>(x2d, Wpb, pb);
  // 5) logits + softmax
  logits_softmax_kernel<<<dim3(BB * HH * II), blk256, 0, stream>>>(
      q, k, qgp, kgp, qgl, kgl, pb, bias, tpw_past, tpw_last, attn);
  // 6) attn-weighted x2d -> pair output (feat[0:768))
  wpair_kernel<<<dim3(BB * II), blk128, 0, stream>>>(x2d, attn, W_pair_value, feat);
  // 7) attn @ v, attn @ point values, inverse transform + norms (feat[768:2304))
  av_kernel<<<dim3(BB * II), blk256, 0, stream>>>(attn, v, vgp, vgl, past_T, past_R, feat);
  // 8) out = feat @ W_out + b_out
  {
    GemmJobs jobs = {};
    jobs.j[0] = {W_out, out, DD};
    for (int z = 1; z < 6; ++z) jobs.j[z] = {W_out, out, DD};
    gemm_batch_kernel<<<dim3(32, 12, 1), blk256, 0, stream>>>(feat, jobs, b_out, FEAT_DIM);
  }
}

// Round 2
// 269.732 us; speedup vs baseline: 1.7958x; 1.7958x over previous
//
#include <hip/hip_runtime.h>
#include <hip/hip_bf16.h>
#include <math.h>

#define BB 2
#define II 256
#define DD 768
#define HH 12
#define DPP 128
#define DKK 64
#define NPQ 4
#define NPV 8
#define FEAT_DIM 2304
#define NPACK 3456            // 2304 (qkv) + 1152 (6 point projections)

// ---------------- workspace layout (float units) ----------------
#define OFF_QKVPTS ((size_t)0)        // [512][3456] f32          -> 1769472
#define OFF_PBATTN ((size_t)1769472)  // [b][h][i][j] f32 (pair bias, then attn in-place) -> +1572864
#define OFF_X1DB   ((size_t)3342336)  // [512][768] bf16          -> +196608
#define OFF_W1T    ((size_t)3538944)  // [3456][768] bf16         -> +1327104
#define OFF_W2T    ((size_t)4866048)  // [768][2304] bf16         -> +884736
#define OFF_FEATB  ((size_t)5750784)  // [512][2304] bf16         -> +589824 (end 6340608 f = 25.4 MB)

#define SCALAR_W 0.07216878364870323f   /* 1/sqrt(192) */
#define POINT_W  0.13608276348795434f   /* 1/sqrt(54)  */
#define PAIR_W   0.57735026918962576f   /* 1/sqrt(3)   */

typedef __attribute__((ext_vector_type(8))) short short8;
typedef __attribute__((ext_vector_type(4))) float f32x4;

__device__ inline ushort f2bf(float f) {
  __hip_bfloat16 h = __float2bfloat16(f);
  return *reinterpret_cast<ushort*>(&h);
}

// ---------- fp32 -> bf16 elementwise (x1d) ----------
__global__ __launch_bounds__(256)
void convert_x_kernel(const float* __restrict__ src, ushort* __restrict__ dst, int n8) {
  const int idx = blockIdx.x * 256 + threadIdx.x;
  if (idx >= n8) return;
  const float4 f0 = reinterpret_cast<const float4*>(src)[idx * 2 + 0];
  const float4 f1 = reinterpret_cast<const float4*>(src)[idx * 2 + 1];
  short8 v;
  v[0] = (short)f2bf(f0.x); v[1] = (short)f2bf(f0.y);
  v[2] = (short)f2bf(f0.z); v[3] = (short)f2bf(f0.w);
  v[4] = (short)f2bf(f1.x); v[5] = (short)f2bf(f1.y);
  v[6] = (short)f2bf(f1.z); v[7] = (short)f2bf(f1.w);
  reinterpret_cast<short8*>(dst)[idx] = v;
}

// ---------- weight transpose + convert: dst[n][k] = bf16(src[k][n]) ----------
struct TJob { const float* src; ushort* dst; int K, N, stride; };
struct TJobs { TJob j[10]; };

__global__ __launch_bounds__(256)
void transpose_pack_kernel(TJobs jobs) {
  const TJob J = jobs.j[blockIdx.z];
  const int k0 = blockIdx.y * 32, n0 = blockIdx.x * 32;
  if (k0 >= J.K || n0 >= J.N) return;
  __shared__ float t[32][33];
  const int tid = threadIdx.x;
  const int c = tid & 31, r = tid >> 5;   // r: 0..7
#pragma unroll
  for (int u = 0; u < 4; ++u) {
    const int kk = r + u * 8;
    t[kk][c] = (n0 + c < J.N) ? J.src[(size_t)(k0 + kk) * J.N + n0 + c] : 0.f;
  }
  __syncthreads();
#pragma unroll
  for (int u = 0; u < 4; ++u) {
    const int n = n0 + r + u * 8;
    if (n < J.N) J.dst[(size_t)n * J.stride + k0 + c] = f2bf(t[c][r + u * 8]);
  }
}

// ---------- MFMA bf16 GEMM: C[m][n] = A[m][:K] . Bt[n][:K] (+bias[n]) ----------
// block 64x64 tile, 256 threads = 4 waves (2x2), wave = 32x32 = 2x2 mfma 16x16x32
__global__ __launch_bounds__(256)
void mfma_gemm_kernel(const ushort* __restrict__ A, const ushort* __restrict__ Bt,
                      float* __restrict__ C, const float* __restrict__ bias,
                      int N, int K) {
  __shared__ short a_s[64 * 64];
  __shared__ short b_s[64 * 64];
  const int tid = threadIdx.x;
  const int lane = tid & 63;
  const int wave = tid >> 6;
  const int wm = wave >> 1, wn = wave & 1;
  const int m0 = blockIdx.x * 64, n0 = blockIdx.y * 64;
  const int lrow = tid >> 3, lch = tid & 7;      // staging: row 0..31, 16B chunk 0..7
  const int l15 = lane & 15, l7 = lane & 7, kq = lane >> 4;
  f32x4 acc[2][2] = {};
  for (int kc = 0; kc < K; kc += 64) {
#pragma unroll
    for (int u = 0; u < 2; ++u) {
      const int r = lrow + u * 32;
      const short8 av = *reinterpret_cast<const short8*>(A  + (size_t)(m0 + r) * K + kc + lch * 8);
      const short8 bv = *reinterpret_cast<const short8*>(Bt + (size_t)(n0 + r) * K + kc + lch * 8);
      const int sc = ((lch ^ (r & 7)) << 3);
      *reinterpret_cast<short8*>(&a_s[r * 64 + sc]) = av;
      *reinterpret_cast<short8*>(&b_s[r * 64 + sc]) = bv;
    }
    __syncthreads();
#pragma unroll
    for (int kk = 0; kk < 64; kk += 32) {
      const int ch = (kk >> 3) + kq;
      const int cx = ((ch ^ l7) << 3);
      short8 af[2], bf[2];
      af[0] = *reinterpret_cast<const short8*>(&a_s[(wm * 32 +      l15) * 64 + cx]);
      af[1] = *reinterpret_cast<const short8*>(&a_s[(wm * 32 + 16 + l15) * 64 + cx]);
      bf[0] = *reinterpret_cast<const short8*>(&b_s[(wn * 32 +      l15) * 64 + cx]);
      bf[1] = *reinterpret_cast<const short8*>(&b_s[(wn * 32 + 16 + l15) * 64 + cx]);
#pragma unroll
      for (int mt = 0; mt < 2; ++mt)
#pragma unroll
        for (int nt = 0; nt < 2; ++nt)
          acc[mt][nt] = __builtin_amdgcn_mfma_f32_16x16x32_bf16(af[mt], bf[nt], acc[mt][nt], 0, 0, 0);
    }
    __syncthreads();
  }
#pragma unroll
  for (int mt = 0; mt < 2; ++mt) {
    const int r0 = m0 + wm * 32 + mt * 16 + kq * 4;
#pragma unroll
    for (int nt = 0; nt < 2; ++nt) {
      const int c = n0 + wn * 32 + nt * 16 + l15;
      const float bv = bias ? bias[c] : 0.f;
#pragma unroll
      for (int rr = 0; rr < 4; ++rr)
        C[(size_t)(r0 + rr) * N + c] = acc[mt][nt][rr] + bv;
    }
  }
}

// ---------- local->global frame transform (in-place, packed cols) ----------
struct XfJob { float* base; const float* T; const float* R; int np; };
struct XfJobs { XfJob j[6]; };

__global__ __launch_bounds__(256)
void transform_kernel(XfJobs jobs) {
  const XfJob J = jobs.j[blockIdx.y];
  const int total = BB * II * HH * J.np;
  const int idx = blockIdx.x * 256 + threadIdx.x;
  if (idx >= total) return;
  const int bi = idx / (HH * J.np);
  const int rem = idx % (HH * J.np);
  float* p = J.base + (size_t)bi * NPACK + rem * 3;
  const float p0 = p[0], p1 = p[1], p2 = p[2];
  const float* R = J.R + (size_t)bi * 9;
  const float* T = J.T + (size_t)bi * 3;
  p[0] = R[0] * p0 + R[3] * p1 + R[6] * p2 + T[0];
  p[1] = R[1] * p0 + R[4] * p1 + R[7] * p2 + T[1];
  p[2] = R[2] * p0 + R[5] * p1 + R[8] * p2 + T[2];
}

// ---------- pair bias: pbattn[b][h][i][j] = pair_w * sum_p x2d[b,i,j,p]*Wpb[p,h] ----------
__global__ __launch_bounds__(256)
void pairbias_kernel(const float* __restrict__ x2d, const float* __restrict__ Wpb,
                     float* __restrict__ pbattn) {
  __shared__ float w_s[DPP][HH];
  const int tid = threadIdx.x;
  for (int idx = tid; idx < DPP * HH; idx += 256) w_s[idx / HH][idx % HH] = Wpb[idx];
  __syncthreads();
  const size_t bi = blockIdx.x;
  const int b = blockIdx.x >> 8, i = blockIdx.x & 255;
  const float* xr = x2d + (bi * II + tid) * DPP;
  float acc[HH];
#pragma unroll
  for (int h = 0; h < HH; ++h) acc[h] = 0.f;
  for (int p = 0; p < DPP; p += 4) {
    const float4 x4 = *reinterpret_cast<const float4*>(&xr[p]);
    const float xs[4] = {x4.x, x4.y, x4.z, x4.w};
#pragma unroll
    for (int u = 0; u < 4; ++u) {
      const float x = xs[u];
      const float4 w0 = *reinterpret_cast<const float4*>(&w_s[p + u][0]);
      const float4 w1 = *reinterpret_cast<const float4*>(&w_s[p + u][4]);
      const float4 w2 = *reinterpret_cast<const float4*>(&w_s[p + u][8]);
      acc[0] += x * w0.x; acc[1] += x * w0.y; acc[2]  += x * w0.z; acc[3]  += x * w0.w;
      acc[4] += x * w1.x; acc[5] += x * w1.y; acc[6]  += x * w1.z; acc[7]  += x * w1.w;
      acc[8] += x * w2.x; acc[9] += x * w2.y; acc[10] += x * w2.z; acc[11] += x * w2.w;
    }
  }
#pragma unroll
  for (int h = 0; h < HH; ++h)
    pbattn[(((size_t)(b * HH + h) * II + i) * II) + tid] = PAIR_W * acc[h];
}

// ---------- logits + softmax (in place over pbattn) ----------
__global__ __launch_bounds__(256)
void logits_softmax_kernel(const float* __restrict__ qkv, const float* __restrict__ bias,
                           const float* __restrict__ tpw_past, const float* __restrict__ tpw_last,
                           float* __restrict__ pbattn) {
  const int blk = blockIdx.x;
  const int i = blk % II;
  const int h = (blk / II) % HH;
  const int b = blk / (II * HH);
  __shared__ float q_s[DKK];
  __shared__ float qgp_s[12];
  __shared__ float qgl_s[12];
  __shared__ float red[256];
  const int tid = threadIdx.x;
  const size_t rowi = (size_t)(b * II + i) * NPACK;
  if (tid < DKK) q_s[tid] = qkv[rowi + h * DKK + tid];
  if (tid >= 64 && tid < 76)  qgp_s[tid - 64] = qkv[rowi + 2304 +   0 + h * 12 + (tid - 64)];
  if (tid >= 96 && tid < 108) qgl_s[tid - 96] = qkv[rowi + 2304 + 576 + h * 12 + (tid - 96)];
  __syncthreads();
  const float pwp = POINT_W * log1pf(expf(tpw_past[h]));
  const float pwl = POINT_W * log1pf(expf(tpw_last[h]));
  const int j = tid;
  const size_t rowj = (size_t)(b * II + j) * NPACK;
  // scalar q.k
  const float4* kr = reinterpret_cast<const float4*>(qkv + rowj + 768 + h * DKK);
  const float4* qs4 = reinterpret_cast<const float4*>(q_s);
  float s = 0.f;
#pragma unroll
  for (int c = 0; c < 16; ++c) {
    const float4 kv = kr[c];
    const float4 qv = qs4[c];
    s += qv.x * kv.x + qv.y * kv.y + qv.z * kv.z + qv.w * kv.w;
  }
  float logit = SCALAR_W * s;
  {
    const float* kp = qkv + rowj + 2304 + 144 + h * 12;
    float d = 0.f;
#pragma unroll
    for (int n = 0; n < NPQ; ++n) {
      const float dx = qgp_s[n * 3 + 0] - kp[n * 3 + 0];
      const float dy = qgp_s[n * 3 + 1] - kp[n * 3 + 1];
      const float dz = qgp_s[n * 3 + 2] - kp[n * 3 + 2];
      d += sqrtf(dx * dx + dy * dy + dz * dz);
    }
    logit -= 0.5f * pwp * d;
  }
  {
    const float* kp = qkv + rowj + 2304 + 720 + h * 12;
    float d = 0.f;
#pragma unroll
    for (int n = 0; n < NPQ; ++n) {
      const float dx = qgl_s[n * 3 + 0] - kp[n * 3 + 0];
      const float dy = qgl_s[n * 3 + 1] - kp[n * 3 + 1];
      const float dz = qgl_s[n * 3 + 2] - kp[n * 3 + 2];
      d += sqrtf(dx * dx + dy * dy + dz * dz);
    }
    logit -= 0.5f * pwl * d;
  }
  const size_t aidx = ((size_t)(b * HH + h) * II + i) * II + j;
  logit += pbattn[aidx];
  logit += bias[aidx];
  red[tid] = logit; __syncthreads();
  for (int off = 128; off > 0; off >>= 1) {
    if (tid < off) red[tid] = fmaxf(red[tid], red[tid + off]);
    __syncthreads();
  }
  const float m = red[0]; __syncthreads();
  const float e = expf(logit - m);
  red[tid] = e; __syncthreads();
  for (int off = 128; off > 0; off >>= 1) {
    if (tid < off) red[tid] += red[tid + off];
    __syncthreads();
  }
  pbattn[aidx] = e / red[0];
}

// ---------- attn-weighted x2d -> pair output (feat cols [0,768)) ----------
__global__ __launch_bounds__(128)
void wpair_kernel(const float* __restrict__ x2d, const float* __restrict__ attn,
                  const float* __restrict__ Wpv, ushort* __restrict__ featb) {
  __shared__ float a_s[HH][II];
  __shared__ float t_s[HH][DPP];
  const int tid = threadIdx.x;
  const int bi = blockIdx.x;
  const int b = bi >> 8, i = bi & 255;
  for (int idx = tid; idx < HH * II; idx += 128) {
    const int h = idx >> 8, j = idx & 255;
    a_s[h][j] = attn[((size_t)(b * HH + h) * II + i) * II + j];
  }
  __syncthreads();
  float acc[HH];
#pragma unroll
  for (int h = 0; h < HH; ++h) acc[h] = 0.f;
  const float* xr = x2d + ((size_t)bi * II) * DPP + tid;
  for (int j = 0; j < II; j += 4) {
    const float x0 = xr[(size_t)(j + 0) * DPP];
    const float x1 = xr[(size_t)(j + 1) * DPP];
    const float x2 = xr[(size_t)(j + 2) * DPP];
    const float x3 = xr[(size_t)(j + 3) * DPP];
#pragma unroll
    for (int h = 0; h < HH; ++h) {
      const float4 a = *reinterpret_cast<const float4*>(&a_s[h][j]);
      acc[h] += a.x * x0 + a.y * x1 + a.z * x2 + a.w * x3;
    }
  }
#pragma unroll
  for (int h = 0; h < HH; ++h) t_s[h][tid] = acc[h];
  __syncthreads();
  ushort* fout = featb + (size_t)bi * FEAT_DIM;
  for (int c = tid; c < DD; c += 128) {
    const int h = c >> 6;
    float o = 0.f;
    for (int p = 0; p < DPP; ++p) o += t_s[h][p] * Wpv[(size_t)p * DD + c];
    fout[c] = f2bf(o);
  }
}

// ---------- attn @ v, attn @ point values, inverse transform + norms ----------
__global__ __launch_bounds__(256)
void av_kernel(const float* __restrict__ attn, const float* __restrict__ qkv,
               const float* __restrict__ past_T, const float* __restrict__ past_R,
               ushort* __restrict__ featb) {
  __shared__ float a_s[HH][II];
  __shared__ float og_s[2][288];
  const int tid = threadIdx.x;
  const int bi = blockIdx.x;
  const int b = bi >> 8, i = bi & 255;
  for (int idx = tid; idx < HH * II; idx += 256) {
    const int h = idx >> 8, j = idx & 255;
    a_s[h][j] = attn[((size_t)(b * HH + h) * II + i) * II + j];
  }
  __syncthreads();
  ushort* fout = featb + (size_t)bi * FEAT_DIM;
  // out_scalar: v at packed col 1536
  for (int c = tid; c < DD; c += 256) {
    const int h = c >> 6;
    const float* vb = qkv + (size_t)b * II * NPACK + 1536 + c;
    float o = 0.f;
    for (int j = 0; j < II; j += 4) {
      const float4 a = *reinterpret_cast<const float4*>(&a_s[h][j]);
      o += a.x * vb[(size_t)(j + 0) * NPACK] + a.y * vb[(size_t)(j + 1) * NPACK]
         + a.z * vb[(size_t)(j + 2) * NPACK] + a.w * vb[(size_t)(j + 3) * NPACK];
    }
    fout[768 + c] = f2bf(o);
  }
  // og for both branches (vgp at 2592, vgl at 3168)
  for (int t = tid; t < 576; t += 256) {
    const int br = t / 288;
    const int r = t % 288;           // h*24 + n*3 + p
    const int h = r / 24;
    const int rem = r % 24;
    const float* vb = qkv + (size_t)b * II * NPACK + (br ? 3168 : 2592) + h * 24 + rem;
    float o = 0.f;
    for (int j = 0; j < II; ++j) o += a_s[h][j] * vb[(size_t)j * NPACK];
    og_s[br][r] = o;
  }
  __syncthreads();
  if (tid < 192) {
    const int br = tid / 96;
    const int r = tid % 96;          // h*8 + n
    const float* T = past_T + (size_t)bi * 3;
    const float* R = past_R + (size_t)bi * 9;
    const float o0 = og_s[br][r * 3 + 0] - T[0];
    const float o1 = og_s[br][r * 3 + 1] - T[1];
    const float o2 = og_s[br][r * 3 + 2] - T[2];
    const float l0 = R[0] * o0 + R[1] * o1 + R[2] * o2;
    const float l1 = R[3] * o0 + R[4] * o1 + R[5] * o2;
    const float l2 = R[6] * o0 + R[7] * o1 + R[8] * o2;
    const float nn = sqrtf(l0 * l0 + l1 * l1 + l2 * l2);
    const int olbase = br ? 1920 : 1536;
    const int nbase  = br ? 2208 : 1824;
    fout[olbase + r * 3 + 0] = f2bf(l0);
    fout[olbase + r * 3 + 1] = f2bf(l1);
    fout[olbase + r * 3 + 2] = f2bf(l2);
    fout[nbase + r] = f2bf(nn);
  }
}

extern "C" void kernel_launch(void* const* d_in, const int* in_sizes, int n_in,
                              void* d_out, int out_size, void* d_ws, size_t ws_size,
                              hipStream_t stream) {
  (void)in_sizes; (void)n_in; (void)out_size; (void)ws_size;
  const float* x1d      = (const float*)d_in[0];
  const float* x2d      = (const float*)d_in[1];
  const float* past_T   = (const float*)d_in[2];
  const float* past_R   = (const float*)d_in[3];
  const float* last_T   = (const float*)d_in[4];
  const float* last_R   = (const float*)d_in[5];
  const float* bias     = (const float*)d_in[6];
  const float* Wq       = (const float*)d_in[7];
  const float* Wk       = (const float*)d_in[8];
  const float* Wv       = (const float*)d_in[9];
  const float* Wpb      = (const float*)d_in[10];
  const float* Wpq_past = (const float*)d_in[11];
  const float* Wpk_past = (const float*)d_in[12];
  const float* Wpv_past = (const float*)d_in[13];
  const float* Wpq_last = (const float*)d_in[14];
  const float* Wpk_last = (const float*)d_in[15];
  const float* Wpv_last = (const float*)d_in[16];
  const float* tpw_past = (const float*)d_in[17];
  const float* tpw_last = (const float*)d_in[18];
  const float* W_pair_value = (const float*)d_in[19];
  const float* W_out    = (const float*)d_in[20];
  const float* b_out    = (const float*)d_in[21];
  float* out = (float*)d_out;
  float* ws  = (float*)d_ws;

  float*  qkvpts = ws + OFF_QKVPTS;
  float*  pbattn = ws + OFF_PBATTN;
  ushort* x1db   = (ushort*)(ws + OFF_X1DB);
  ushort* w1t    = (ushort*)(ws + OFF_W1T);
  ushort* w2t    = (ushort*)(ws + OFF_W2T);
  ushort* featb  = (ushort*)(ws + OFF_FEATB);

  const dim3 blk256(256), blk128(128);

  // 1) x1d -> bf16
  convert_x_kernel<<<dim3(192), blk256, 0, stream>>>(x1d, x1db, 512 * 768 / 8);

  // 2) transpose+convert all weights into packed Wt[n][k]
  {
    TJobs jobs = {};
    jobs.j[0] = {Wq,       w1t + (size_t)   0 * 768, DD,      DD,  768};
    jobs.j[1] = {Wk,       w1t + (size_t) 768 * 768, DD,      DD,  768};
    jobs.j[2] = {Wv,       w1t + (size_t)1536 * 768, DD,      DD,  768};
    jobs.j[3] = {Wpq_past, w1t + (size_t)2304 * 768, DD,     144,  768};
    jobs.j[4] = {Wpk_past, w1t + (size_t)2448 * 768, DD,     144,  768};
    jobs.j[5] = {Wpv_past, w1t + (size_t)2592 * 768, DD,     288,  768};
    jobs.j[6] = {Wpq_last, w1t + (size_t)2880 * 768, DD,     144,  768};
    jobs.j[7] = {Wpk_last, w1t + (size_t)3024 * 768, DD,     144,  768};
    jobs.j[8] = {Wpv_last, w1t + (size_t)3168 * 768, DD,     288,  768};
    jobs.j[9] = {W_out,    w2t,                      FEAT_DIM, DD, 2304};
    transpose_pack_kernel<<<dim3(24, 72, 10), blk256, 0, stream>>>(jobs);
  }

  // 3) fused GEMM: qkvpts[512][3456] = x1d_bf16 @ [Wq|Wk|Wv|pts...]
  mfma_gemm_kernel<<<dim3(8, 54), blk256, 0, stream>>>(x1db, w1t, qkvpts, nullptr, NPACK, DD);

  // 4) frame transforms (in place on packed point cols)
  {
    XfJobs jobs = {};
    jobs.j[0] = {qkvpts + 2304 +   0, past_T, past_R, NPQ};
    jobs.j[1] = {qkvpts + 2304 + 144, past_T, past_R, NPQ};
    jobs.j[2] = {qkvpts + 2304 + 288, past_T, past_R, NPV};
    jobs.j[3] = {qkvpts + 2304 + 576, last_T, last_R, NPQ};
    jobs.j[4] = {qkvpts + 2304 + 720, last_T, last_R, NPQ};
    jobs.j[5] = {qkvpts + 2304 + 864, last_T, last_R, NPV};
    transform_kernel<<<dim3(192, 6), blk256, 0, stream>>>(jobs);
  }

  // 5) pair bias (written directly in [b][h][i][j] layout)
  pairbias_kernel<<<dim3(BB * II), blk256, 0, stream>>>(x2d, Wpb, pbattn);

  // 6) logits + softmax (in place)
  logits_softmax_kernel<<<dim3(BB * HH * II), blk256, 0, stream>>>(
      qkvpts, bias, tpw_past, tpw_last, pbattn);

  // 7) attn-weighted x2d -> feat[0:768)
  wpair_kernel<<<dim3(BB * II), blk128, 0, stream>>>(x2d, pbattn, W_pair_value, featb);

  // 8) attn @ v / point values + inverse transform -> feat[768:2304)
  av_kernel<<<dim3(BB * II), blk256, 0, stream>>>(pbattn, qkvpts, past_T, past_R, featb);

  // 9) out = feat @ W_out + b_out
  mfma_gemm_kernel<<<dim3(8, 12), blk256, 0, stream>>>(featb, w2t, out, b_out, DD, FEAT_DIM);
}

// Round 3
// 225.965 us; speedup vs baseline: 2.1436x; 1.1937x over previous
//
#include <hip/hip_runtime.h>
#include <hip/hip_bf16.h>
#include <math.h>

#define BB 2
#define II 256
#define DD 768
#define HH 12
#define DPP 128
#define DKK 64
#define NPQ 4
#define NPV 8
#define FEAT_DIM 2304
#define NPACK 3456            // 2304 (qkv) + 1152 (6 point projections)

// ---------------- workspace layout (float units) ----------------
#define OFF_QKVPTS ((size_t)0)        // [512][3456] f32
#define OFF_PBATTN ((size_t)1769472)  // [b][h][i][j] f32 (pair bias, then attn in-place)
#define OFF_X1DB   ((size_t)3342336)  // [512][768] bf16
#define OFF_W1T    ((size_t)3538944)  // [3456][768] bf16
#define OFF_W2T    ((size_t)4866048)  // [768][2304] bf16
#define OFF_FEATB  ((size_t)5750784)  // [512][2304] bf16
#define OFF_QPTS   ((size_t)6340608)  // [b][h][i][24] f32 (past 0..12, last 12..24)
#define OFF_KPTS   ((size_t)6488064)  // [b][h][j][24] f32  (end 6635520 f = 26.5 MB)

#define SCALAR_W 0.07216878364870323f   /* 1/sqrt(192) */
#define POINT_W  0.13608276348795434f   /* 1/sqrt(54)  */
#define PAIR_W   0.57735026918962576f   /* 1/sqrt(3)   */

typedef __attribute__((ext_vector_type(8))) short short8;
typedef __attribute__((ext_vector_type(4))) float f32x4;
typedef __attribute__((ext_vector_type(16))) float f32x16;

__device__ inline ushort f2bf(float f) {
  __hip_bfloat16 h = __float2bfloat16(f);
  return *reinterpret_cast<ushort*>(&h);
}

// ---------- fp32 -> bf16 elementwise (x1d) ----------
__global__ __launch_bounds__(256)
void convert_x_kernel(const float* __restrict__ src, ushort* __restrict__ dst, int n8) {
  const int idx = blockIdx.x * 256 + threadIdx.x;
  if (idx >= n8) return;
  const float4 f0 = reinterpret_cast<const float4*>(src)[idx * 2 + 0];
  const float4 f1 = reinterpret_cast<const float4*>(src)[idx * 2 + 1];
  short8 v;
  v[0] = (short)f2bf(f0.x); v[1] = (short)f2bf(f0.y);
  v[2] = (short)f2bf(f0.z); v[3] = (short)f2bf(f0.w);
  v[4] = (short)f2bf(f1.x); v[5] = (short)f2bf(f1.y);
  v[6] = (short)f2bf(f1.z); v[7] = (short)f2bf(f1.w);
  reinterpret_cast<short8*>(dst)[idx] = v;
}

// ---------- weight transpose + convert: dst[n][k] = bf16(src[k][n]) ----------
struct TJob { const float* src; ushort* dst; int K, N, stride; };
struct TJobs { TJob j[10]; };

__global__ __launch_bounds__(256)
void transpose_pack_kernel(TJobs jobs) {
  const TJob J = jobs.j[blockIdx.z];
  const int k0 = blockIdx.y * 32, n0 = blockIdx.x * 32;
  if (k0 >= J.K || n0 >= J.N) return;
  __shared__ float t[32][33];
  const int tid = threadIdx.x;
  const int c = tid & 31, r = tid >> 5;   // r: 0..7
#pragma unroll
  for (int u = 0; u < 4; ++u) {
    const int kk = r + u * 8;
    t[kk][c] = (n0 + c < J.N) ? J.src[(size_t)(k0 + kk) * J.N + n0 + c] : 0.f;
  }
  __syncthreads();
#pragma unroll
  for (int u = 0; u < 4; ++u) {
    const int n = n0 + r + u * 8;
    if (n < J.N) J.dst[(size_t)n * J.stride + k0 + c] = f2bf(t[c][r + u * 8]);
  }
}

// ---------- MFMA bf16 GEMM: C[m][n] = A[m][:K] . Bt[n][:K] (+bias[n]) ----------
__global__ __launch_bounds__(256)
void mfma_gemm_kernel(const ushort* __restrict__ A, const ushort* __restrict__ Bt,
                      float* __restrict__ C, const float* __restrict__ bias,
                      int N, int K) {
  __shared__ short a_s[64 * 64];
  __shared__ short b_s[64 * 64];
  const int tid = threadIdx.x;
  const int lane = tid & 63;
  const int wave = tid >> 6;
  const int wm = wave >> 1, wn = wave & 1;
  const int m0 = blockIdx.x * 64, n0 = blockIdx.y * 64;
  const int lrow = tid >> 3, lch = tid & 7;
  const int l15 = lane & 15, l7 = lane & 7, kq = lane >> 4;
  f32x4 acc[2][2] = {};
  for (int kc = 0; kc < K; kc += 64) {
#pragma unroll
    for (int u = 0; u < 2; ++u) {
      const int r = lrow + u * 32;
      const short8 av = *reinterpret_cast<const short8*>(A  + (size_t)(m0 + r) * K + kc + lch * 8);
      const short8 bv = *reinterpret_cast<const short8*>(Bt + (size_t)(n0 + r) * K + kc + lch * 8);
      const int sc = ((lch ^ (r & 7)) << 3);
      *reinterpret_cast<short8*>(&a_s[r * 64 + sc]) = av;
      *reinterpret_cast<short8*>(&b_s[r * 64 + sc]) = bv;
    }
    __syncthreads();
#pragma unroll
    for (int kk = 0; kk < 64; kk += 32) {
      const int ch = (kk >> 3) + kq;
      const int cx = ((ch ^ l7) << 3);
      short8 af[2], bf[2];
      af[0] = *reinterpret_cast<const short8*>(&a_s[(wm * 32 +      l15) * 64 + cx]);
      af[1] = *reinterpret_cast<const short8*>(&a_s[(wm * 32 + 16 + l15) * 64 + cx]);
      bf[0] = *reinterpret_cast<const short8*>(&b_s[(wn * 32 +      l15) * 64 + cx]);
      bf[1] = *reinterpret_cast<const short8*>(&b_s[(wn * 32 + 16 + l15) * 64 + cx]);
#pragma unroll
      for (int mt = 0; mt < 2; ++mt)
#pragma unroll
        for (int nt = 0; nt < 2; ++nt)
          acc[mt][nt] = __builtin_amdgcn_mfma_f32_16x16x32_bf16(af[mt], bf[nt], acc[mt][nt], 0, 0, 0);
    }
    __syncthreads();
  }
#pragma unroll
  for (int mt = 0; mt < 2; ++mt) {
    const int r0 = m0 + wm * 32 + mt * 16 + kq * 4;
#pragma unroll
    for (int nt = 0; nt < 2; ++nt) {
      const int c = n0 + wn * 32 + nt * 16 + l15;
      const float bv = bias ? bias[c] : 0.f;
#pragma unroll
      for (int rr = 0; rr < 4; ++rr)
        C[(size_t)(r0 + rr) * N + c] = acc[mt][nt][rr] + bv;
    }
  }
}

// ---------- local->global frame transform ----------
struct XfJob { float* base; const float* T; const float* R; int np; float* hm; int sub; };
struct XfJobs { XfJob j[6]; };

__global__ __launch_bounds__(256)
void transform_kernel(XfJobs jobs) {
  const XfJob J = jobs.j[blockIdx.y];
  const int total = BB * II * HH * J.np;
  const int idx = blockIdx.x * 256 + threadIdx.x;
  if (idx >= total) return;
  const int hn = HH * J.np;
  const int bi = idx / hn;
  const int rem = idx - bi * hn;
  float* p = J.base + (size_t)bi * NPACK + rem * 3;
  const float p0 = p[0], p1 = p[1], p2 = p[2];
  const float* R = J.R + (size_t)bi * 9;
  const float* T = J.T + (size_t)bi * 3;
  const float o0 = R[0] * p0 + R[3] * p1 + R[6] * p2 + T[0];
  const float o1 = R[1] * p0 + R[4] * p1 + R[7] * p2 + T[1];
  const float o2 = R[2] * p0 + R[5] * p1 + R[8] * p2 + T[2];
  if (J.hm) {
    const int h = rem / J.np, n = rem - h * J.np;
    const int b = bi >> 8, i = bi & 255;
    float* d = J.hm + ((size_t)(b * HH + h) * II + i) * 24 + J.sub + n * 3;
    d[0] = o0; d[1] = o1; d[2] = o2;
  } else {
    p[0] = o0; p[1] = o1; p[2] = o2;
  }
}

// ---------- pair bias: pbattn[b][h][i][j] = pair_w * sum_p x2d[b,i,j,p]*Wpb[p,h] ----------
__global__ __launch_bounds__(256)
void pairbias_kernel(const float* __restrict__ x2d, const float* __restrict__ Wpb,
                     float* __restrict__ pbattn) {
  __shared__ float w_s[DPP][HH];
  const int tid = threadIdx.x;
  for (int idx = tid; idx < DPP * HH; idx += 256) w_s[idx / HH][idx % HH] = Wpb[idx];
  __syncthreads();
  const size_t bi = blockIdx.x;
  const int b = blockIdx.x >> 8, i = blockIdx.x & 255;
  const float* xr = x2d + (bi * II + tid) * DPP;
  float acc[HH];
#pragma unroll
  for (int h = 0; h < HH; ++h) acc[h] = 0.f;
  for (int p = 0; p < DPP; p += 4) {
    const float4 x4 = *reinterpret_cast<const float4*>(&xr[p]);
    const float xs[4] = {x4.x, x4.y, x4.z, x4.w};
#pragma unroll
    for (int u = 0; u < 4; ++u) {
      const float x = xs[u];
      const float4 w0 = *reinterpret_cast<const float4*>(&w_s[p + u][0]);
      const float4 w1 = *reinterpret_cast<const float4*>(&w_s[p + u][4]);
      const float4 w2 = *reinterpret_cast<const float4*>(&w_s[p + u][8]);
      acc[0] += x * w0.x; acc[1] += x * w0.y; acc[2]  += x * w0.z; acc[3]  += x * w0.w;
      acc[4] += x * w1.x; acc[5] += x * w1.y; acc[6]  += x * w1.z; acc[7]  += x * w1.w;
      acc[8] += x * w2.x; acc[9] += x * w2.y; acc[10] += x * w2.z; acc[11] += x * w2.w;
    }
  }
#pragma unroll
  for (int h = 0; h < HH; ++h)
    pbattn[(((size_t)(b * HH + h) * II + i) * II) + tid] = PAIR_W * acc[h];
}

// ---------- fused attention: QK^T (MFMA) + point dists + bias + softmax ----------
// grid (8 itiles, 12 h, 2 b), 256 threads = 4 waves; wave w owns j in [w*64, w*64+64)
__global__ __launch_bounds__(256)
void attn_kernel(const float* __restrict__ qkv,
                 const float* __restrict__ qpts, const float* __restrict__ kpts,
                 const float* __restrict__ bias,
                 const float* __restrict__ tpw_past, const float* __restrict__ tpw_last,
                 float* __restrict__ pbattn) {
  __shared__ ushort kb_s[256 * 64];
  __shared__ ushort qb_s[32 * 64];
  __shared__ float  kp_s[256 * 24];
  __shared__ float  qp_s[32 * 24];
  __shared__ float  red_s[2][32 * 5];
  const int tid = threadIdx.x;
  const int lane = tid & 63;
  const int w = tid >> 6;
  const int i0 = blockIdx.x * 32;
  const int h = blockIdx.y;
  const int b = blockIdx.z;
  const size_t bh = (size_t)b * HH + h;

  // stage K scalars (f32 -> bf16, XOR-swizzled 16B chunks)
  for (int c = tid; c < 2048; c += 256) {
    const int r = c >> 3, ch = c & 7;
    const float* src = qkv + (size_t)(b * II + r) * NPACK + 768 + h * 64 + ch * 8;
    const float4 f0 = *reinterpret_cast<const float4*>(src);
    const float4 f1 = *reinterpret_cast<const float4*>(src + 4);
    short8 v;
    v[0] = (short)f2bf(f0.x); v[1] = (short)f2bf(f0.y);
    v[2] = (short)f2bf(f0.z); v[3] = (short)f2bf(f0.w);
    v[4] = (short)f2bf(f1.x); v[5] = (short)f2bf(f1.y);
    v[6] = (short)f2bf(f1.z); v[7] = (short)f2bf(f1.w);
    *reinterpret_cast<short8*>(&kb_s[r * 64 + ((ch ^ (r & 7)) << 3)]) = v;
  }
  // stage Q scalars (32 rows)
  {
    const int r = tid >> 3, ch = tid & 7;
    const float* src = qkv + (size_t)(b * II + i0 + r) * NPACK + h * 64 + ch * 8;
    const float4 f0 = *reinterpret_cast<const float4*>(src);
    const float4 f1 = *reinterpret_cast<const float4*>(src + 4);
    short8 v;
    v[0] = (short)f2bf(f0.x); v[1] = (short)f2bf(f0.y);
    v[2] = (short)f2bf(f0.z); v[3] = (short)f2bf(f0.w);
    v[4] = (short)f2bf(f1.x); v[5] = (short)f2bf(f1.y);
    v[6] = (short)f2bf(f1.z); v[7] = (short)f2bf(f1.w);
    *reinterpret_cast<short8*>(&qb_s[r * 64 + ((ch ^ (r & 7)) << 3)]) = v;
  }
  // stage K/Q points (f32, head-major, coalesced)
  {
    const float* kpsrc = kpts + bh * (II * 24);
    for (int c = tid; c < 1536; c += 256)
      *reinterpret_cast<float4*>(&kp_s[c * 4]) = reinterpret_cast<const float4*>(kpsrc)[c];
    if (tid < 192) {
      const float* qpsrc = qpts + bh * (II * 24) + (size_t)i0 * 24;
      *reinterpret_cast<float4*>(&qp_s[tid * 4]) = reinterpret_cast<const float4*>(qpsrc)[tid];
    }
  }
  __syncthreads();

  const int l31 = lane & 31, lh = lane >> 5;
  const int j0 = w * 64 + l31;
  const int j1 = j0 + 32;
  // QK^T via mfma 32x32x16: acc0 -> j0 block, acc1 -> j1 block
  f32x16 acc0 = {}, acc1 = {};
#pragma unroll
  for (int kk = 0; kk < 64; kk += 16) {
    const int ach = (kk >> 3) + lh;
    const short8 af  = *reinterpret_cast<const short8*>(&qb_s[l31 * 64 + ((ach ^ (l31 & 7)) << 3)]);
    const short8 bf0 = *reinterpret_cast<const short8*>(&kb_s[j0 * 64 + ((ach ^ (j0 & 7)) << 3)]);
    const short8 bf1 = *reinterpret_cast<const short8*>(&kb_s[j1 * 64 + ((ach ^ (j1 & 7)) << 3)]);
    acc0 = __builtin_amdgcn_mfma_f32_32x32x16_bf16(af, bf0, acc0, 0, 0, 0);
    acc1 = __builtin_amdgcn_mfma_f32_32x32x16_bf16(af, bf1, acc1, 0, 0, 0);
  }
  // k-point registers for this thread's two j columns
  float kg0[24], kg1[24];
#pragma unroll
  for (int c = 0; c < 24; ++c) kg0[c] = kp_s[j0 * 24 + c];
#pragma unroll
  for (int c = 0; c < 24; ++c) kg1[c] = kp_s[j1 * 24 + c];
  const float pwp = 0.5f * POINT_W * log1pf(expf(tpw_past[h]));
  const float pwl = 0.5f * POINT_W * log1pf(expf(tpw_last[h]));
  const float* pbrow = pbattn + bh * (II * II);
  const float* brow  = bias   + bh * (II * II);
  float lg0[16], lg1[16];
#pragma unroll
  for (int reg = 0; reg < 16; ++reg) {
    const int il = (reg & 3) + 8 * (reg >> 2) + 4 * lh;
    const int gi = i0 + il;
    float qg[24];
#pragma unroll
    for (int c = 0; c < 24; ++c) qg[c] = qp_s[il * 24 + c];
    float dp0 = 0.f, dp1 = 0.f, dl0 = 0.f, dl1 = 0.f;
#pragma unroll
    for (int n = 0; n < 4; ++n) {
      const float ax = qg[n * 3], ay = qg[n * 3 + 1], az = qg[n * 3 + 2];
      float dx = ax - kg0[n * 3], dy = ay - kg0[n * 3 + 1], dz = az - kg0[n * 3 + 2];
      dp0 += sqrtf(dx * dx + dy * dy + dz * dz);
      dx = ax - kg1[n * 3]; dy = ay - kg1[n * 3 + 1]; dz = az - kg1[n * 3 + 2];
      dp1 += sqrtf(dx * dx + dy * dy + dz * dz);
      const float bx = qg[12 + n * 3], by = qg[12 + n * 3 + 1], bz = qg[12 + n * 3 + 2];
      dx = bx - kg0[12 + n * 3]; dy = by - kg0[12 + n * 3 + 1]; dz = bz - kg0[12 + n * 3 + 2];
      dl0 += sqrtf(dx * dx + dy * dy + dz * dz);
      dx = bx - kg1[12 + n * 3]; dy = by - kg1[12 + n * 3 + 1]; dz = bz - kg1[12 + n * 3 + 2];
      dl1 += sqrtf(dx * dx + dy * dy + dz * dz);
    }
    lg0[reg] = SCALAR_W * acc0[reg] - pwp * dp0 - pwl * dl0
             + pbrow[(size_t)gi * II + j0] + brow[(size_t)gi * II + j0];
    lg1[reg] = SCALAR_W * acc1[reg] - pwp * dp1 - pwl * dl1
             + pbrow[(size_t)gi * II + j1] + brow[(size_t)gi * II + j1];
  }
  // row max (half-wave shuffle + cross-wave LDS)
#pragma unroll
  for (int reg = 0; reg < 16; ++reg) {
    const int il = (reg & 3) + 8 * (reg >> 2) + 4 * lh;
    float m = fmaxf(lg0[reg], lg1[reg]);
    m = fmaxf(m, __shfl_xor(m, 1));
    m = fmaxf(m, __shfl_xor(m, 2));
    m = fmaxf(m, __shfl_xor(m, 4));
    m = fmaxf(m, __shfl_xor(m, 8));
    m = fmaxf(m, __shfl_xor(m, 16));
    if (l31 == 0) red_s[0][il * 5 + w] = m;
  }
  __syncthreads();
#pragma unroll
  for (int reg = 0; reg < 16; ++reg) {
    const int il = (reg & 3) + 8 * (reg >> 2) + 4 * lh;
    const float m = fmaxf(fmaxf(red_s[0][il * 5 + 0], red_s[0][il * 5 + 1]),
                          fmaxf(red_s[0][il * 5 + 2], red_s[0][il * 5 + 3]));
    const float e0 = __expf(lg0[reg] - m);
    const float e1 = __expf(lg1[reg] - m);
    lg0[reg] = e0; lg1[reg] = e1;
    float s = e0 + e1;
    s += __shfl_xor(s, 1); s += __shfl_xor(s, 2); s += __shfl_xor(s, 4);
    s += __shfl_xor(s, 8); s += __shfl_xor(s, 16);
    if (l31 == 0) red_s[1][il * 5 + w] = s;
  }
  __syncthreads();
  float* arow = pbattn + bh * (II * II);
#pragma unroll
  for (int reg = 0; reg < 16; ++reg) {
    const int il = (reg & 3) + 8 * (reg >> 2) + 4 * lh;
    const int gi = i0 + il;
    const float s = red_s[1][il * 5 + 0] + red_s[1][il * 5 + 1]
                  + red_s[1][il * 5 + 2] + red_s[1][il * 5 + 3];
    const float inv = 1.f / s;
    arow[(size_t)gi * II + j0] = lg0[reg] * inv;
    arow[(size_t)gi * II + j1] = lg1[reg] * inv;
  }
}

// ---------- attn-weighted x2d -> pair output (feat cols [0,768)) ----------
__global__ __launch_bounds__(128)
void wpair_kernel(const float* __restrict__ x2d, const float* __restrict__ attn,
                  const float* __restrict__ Wpv, ushort* __restrict__ featb) {
  __shared__ float a_s[HH][II];
  __shared__ float t_s[HH][DPP];
  const int tid = threadIdx.x;
  const int bi = blockIdx.x;
  const int b = bi >> 8, i = bi & 255;
  for (int idx = tid; idx < HH * II; idx += 128) {
    const int h = idx >> 8, j = idx & 255;
    a_s[h][j] = attn[((size_t)(b * HH + h) * II + i) * II + j];
  }
  __syncthreads();
  float acc[HH];
#pragma unroll
  for (int h = 0; h < HH; ++h) acc[h] = 0.f;
  const float* xr = x2d + ((size_t)bi * II) * DPP + tid;
  for (int j = 0; j < II; j += 4) {
    const float x0 = xr[(size_t)(j + 0) * DPP];
    const float x1 = xr[(size_t)(j + 1) * DPP];
    const float x2 = xr[(size_t)(j + 2) * DPP];
    const float x3 = xr[(size_t)(j + 3) * DPP];
#pragma unroll
    for (int h = 0; h < HH; ++h) {
      const float4 a = *reinterpret_cast<const float4*>(&a_s[h][j]);
      acc[h] += a.x * x0 + a.y * x1 + a.z * x2 + a.w * x3;
    }
  }
#pragma unroll
  for (int h = 0; h < HH; ++h) t_s[h][tid] = acc[h];
  __syncthreads();
  ushort* fout = featb + (size_t)bi * FEAT_DIM;
  for (int c = tid; c < DD; c += 128) {
    const int h = c >> 6;
    float o = 0.f;
    for (int p = 0; p < DPP; ++p) o += t_s[h][p] * Wpv[(size_t)p * DD + c];
    fout[c] = f2bf(o);
  }
}

// ---------- attn @ v, attn @ point values, inverse transform + norms ----------
__global__ __launch_bounds__(256)
void av_kernel(const float* __restrict__ attn, const float* __restrict__ qkv,
               const float* __restrict__ past_T, const float* __restrict__ past_R,
               ushort* __restrict__ featb) {
  __shared__ float a_s[HH][II];
  __shared__ float og_s[2][288];
  const int tid = threadIdx.x;
  const int bi = blockIdx.x;
  const int b = bi >> 8, i = bi & 255;
  for (int idx = tid; idx < HH * II; idx += 256) {
    const int h = idx >> 8, j = idx & 255;
    a_s[h][j] = attn[((size_t)(b * HH + h) * II + i) * II + j];
  }
  __syncthreads();
  ushort* fout = featb + (size_t)bi * FEAT_DIM;
  for (int c = tid; c < DD; c += 256) {
    const int h = c >> 6;
    const float* vb = qkv + (size_t)b * II * NPACK + 1536 + c;
    float o = 0.f;
    for (int j = 0; j < II; j += 4) {
      const float4 a = *reinterpret_cast<const float4*>(&a_s[h][j]);
      o += a.x * vb[(size_t)(j + 0) * NPACK] + a.y * vb[(size_t)(j + 1) * NPACK]
         + a.z * vb[(size_t)(j + 2) * NPACK] + a.w * vb[(size_t)(j + 3) * NPACK];
    }
    fout[768 + c] = f2bf(o);
  }
  for (int t = tid; t < 576; t += 256) {
    const int br = t / 288;
    const int r = t % 288;
    const int h = r / 24;
    const int rem = r % 24;
    const float* vb = qkv + (size_t)b * II * NPACK + (br ? 3168 : 2592) + h * 24 + rem;
    float o = 0.f;
    for (int j = 0; j < II; ++j) o += a_s[h][j] * vb[(size_t)j * NPACK];
    og_s[br][r] = o;
  }
  __syncthreads();
  if (tid < 192) {
    const int br = tid / 96;
    const int r = tid % 96;
    const float* T = past_T + (size_t)bi * 3;
    const float* R = past_R + (size_t)bi * 9;
    const float o0 = og_s[br][r * 3 + 0] - T[0];
    const float o1 = og_s[br][r * 3 + 1] - T[1];
    const float o2 = og_s[br][r * 3 + 2] - T[2];
    const float l0 = R[0] * o0 + R[1] * o1 + R[2] * o2;
    const float l1 = R[3] * o0 + R[4] * o1 + R[5] * o2;
    const float l2 = R[6] * o0 + R[7] * o1 + R[8] * o2;
    const float nn = sqrtf(l0 * l0 + l1 * l1 + l2 * l2);
    const int olbase = br ? 1920 : 1536;
    const int nbase  = br ? 2208 : 1824;
    fout[olbase + r * 3 + 0] = f2bf(l0);
    fout[olbase + r * 3 + 1] = f2bf(l1);
    fout[olbase + r * 3 + 2] = f2bf(l2);
    fout[nbase + r] = f2bf(nn);
  }
}

extern "C" void kernel_launch(void* const* d_in, const int* in_sizes, int n_in,
                              void* d_out, int out_size, void* d_ws, size_t ws_size,
                              hipStream_t stream) {
  (void)in_sizes; (void)n_in; (void)out_size; (void)ws_size;
  const float* x1d      = (const float*)d_in[0];
  const float* x2d      = (const float*)d_in[1];
  const float* past_T   = (const float*)d_in[2];
  const float* past_R   = (const float*)d_in[3];
  const float* last_T   = (const float*)d_in[4];
  const float* last_R   = (const float*)d_in[5];
  const float* bias     = (const float*)d_in[6];
  const float* Wq       = (const float*)d_in[7];
  const float* Wk       = (const float*)d_in[8];
  const float* Wv       = (const float*)d_in[9];
  const float* Wpb      = (const float*)d_in[10];
  const float* Wpq_past = (const float*)d_in[11];
  const float* Wpk_past = (const float*)d_in[12];
  const float* Wpv_past = (const float*)d_in[13];
  const float* Wpq_last = (const float*)d_in[14];
  const float* Wpk_last = (const float*)d_in[15];
  const float* Wpv_last = (const float*)d_in[16];
  const float* tpw_past = (const float*)d_in[17];
  const float* tpw_last = (const float*)d_in[18];
  const float* W_pair_value = (const float*)d_in[19];
  const float* W_out    = (const float*)d_in[20];
  const float* b_out    = (const float*)d_in[21];
  float* out = (float*)d_out;
  float* ws  = (float*)d_ws;

  float*  qkvpts = ws + OFF_QKVPTS;
  float*  pbattn = ws + OFF_PBATTN;
  ushort* x1db   = (ushort*)(ws + OFF_X1DB);
  ushort* w1t    = (ushort*)(ws + OFF_W1T);
  ushort* w2t    = (ushort*)(ws + OFF_W2T);
  ushort* featb  = (ushort*)(ws + OFF_FEATB);
  float*  qpts   = ws + OFF_QPTS;
  float*  kpts   = ws + OFF_KPTS;

  const dim3 blk256(256), blk128(128);

  // 1) x1d -> bf16
  convert_x_kernel<<<dim3(192), blk256, 0, stream>>>(x1d, x1db, 512 * 768 / 8);

  // 2) transpose+convert all weights into packed Wt[n][k]
  {
    TJobs jobs = {};
    jobs.j[0] = {Wq,       w1t + (size_t)   0 * 768, DD,      DD,  768};
    jobs.j[1] = {Wk,       w1t + (size_t) 768 * 768, DD,      DD,  768};
    jobs.j[2] = {Wv,       w1t + (size_t)1536 * 768, DD,      DD,  768};
    jobs.j[3] = {Wpq_past, w1t + (size_t)2304 * 768, DD,     144,  768};
    jobs.j[4] = {Wpk_past, w1t + (size_t)2448 * 768, DD,     144,  768};
    jobs.j[5] = {Wpv_past, w1t + (size_t)2592 * 768, DD,     288,  768};
    jobs.j[6] = {Wpq_last, w1t + (size_t)2880 * 768, DD,     144,  768};
    jobs.j[7] = {Wpk_last, w1t + (size_t)3024 * 768, DD,     144,  768};
    jobs.j[8] = {Wpv_last, w1t + (size_t)3168 * 768, DD,     288,  768};
    jobs.j[9] = {W_out,    w2t,                      FEAT_DIM, DD, 2304};
    transpose_pack_kernel<<<dim3(24, 72, 10), blk256, 0, stream>>>(jobs);
  }

  // 3) fused GEMM: qkvpts[512][3456] = x1d_bf16 @ [Wq|Wk|Wv|pts...]
  mfma_gemm_kernel<<<dim3(8, 54), blk256, 0, stream>>>(x1db, w1t, qkvpts, nullptr, NPACK, DD);

  // 4) frame transforms (q/k points -> head-major buffers; v points in place)
  {
    XfJobs jobs = {};
    jobs.j[0] = {qkvpts + 2304 +   0, past_T, past_R, NPQ, qpts, 0};
    jobs.j[1] = {qkvpts + 2304 + 144, past_T, past_R, NPQ, kpts, 0};
    jobs.j[2] = {qkvpts + 2304 + 288, past_T, past_R, NPV, nullptr, 0};
    jobs.j[3] = {qkvpts + 2304 + 576, last_T, last_R, NPQ, qpts, 12};
    jobs.j[4] = {qkvpts + 2304 + 720, last_T, last_R, NPQ, kpts, 12};
    jobs.j[5] = {qkvpts + 2304 + 864, last_T, last_R, NPV, nullptr, 0};
    transform_kernel<<<dim3(192, 6), blk256, 0, stream>>>(jobs);
  }

  // 5) pair bias (written directly in [b][h][i][j] layout)
  pairbias_kernel<<<dim3(BB * II), blk256, 0, stream>>>(x2d, Wpb, pbattn);

  // 6) fused attention (in-place softmax over pbattn)
  attn_kernel<<<dim3(8, HH, BB), blk256, 0, stream>>>(
      qkvpts, qpts, kpts, bias, tpw_past, tpw_last, pbattn);

  // 7) attn-weighted x2d -> feat[0:768)
  wpair_kernel<<<dim3(BB * II), blk128, 0, stream>>>(x2d, pbattn, W_pair_value, featb);

  // 8) attn @ v / point values + inverse transform -> feat[768:2304)
  av_kernel<<<dim3(BB * II), blk256, 0, stream>>>(pbattn, qkvpts, past_T, past_R, featb);

  // 9) out = feat @ W_out + b_out
  mfma_gemm_kernel<<<dim3(8, 12), blk256, 0, stream>>>(featb, w2t, out, b_out, DD, FEAT_DIM);
}